// Round 3
// baseline (395.016 us; speedup 1.0000x reference)
//
#include <hip/hip_runtime.h>
#include <hip/hip_bf16.h>

// RGCN fused: per-relation aggregate (gather, fp32 acc) -> MFMA GEMM (K = 8*64 = 512)
// Inputs x/linear are fp32 on device (proven by round-1 NaN mechanism); output fp32
// (proven by round-2 absmax matching the bf16-pair-misread statistics exactly).
// Runtime detection kept for robustness. Output: float stores.
// Tile: 64 destination nodes per block, 512 threads (8 waves, 8 nodes/wave).
// LDS: agg[64][520] bf16 + Wt[64][520] bf16 + invdeg[64] f32 = ~130.3 KB dynamic.

#define THREADS 512
#define NPB 64            // nodes per block
#define KDIM 512          // NUM_REL * IN_CH
#define LDA 520           // padded bf16 row stride

typedef __attribute__((ext_vector_type(8))) short bf16x8;
typedef __attribute__((ext_vector_type(4))) float f32x4;

extern __shared__ __align__(16) char smem[];

#define ACC_SWITCH(r, v)                                   \
  switch (r) {                                             \
    case 0: a0 += (v); break; case 1: a1 += (v); break;    \
    case 2: a2 += (v); break; case 3: a3 += (v); break;    \
    case 4: a4 += (v); break; case 5: a5 += (v); break;    \
    case 6: a6 += (v); break; default: a7 += (v); break;   \
  }

__global__ __launch_bounds__(THREADS, 1)
void rgcn_fused(const void* __restrict__ xv,
                const void* __restrict__ wv,    // [512][64] = [r*64+k_in][c_out]
                const int* __restrict__ p32,
                const int* __restrict__ i32,
                const int* __restrict__ t32,
                float* __restrict__ out,
                int num_nodes) {
  __hip_bfloat16* aggS = (__hip_bfloat16*)smem;             // [NPB][LDA]
  __hip_bfloat16* wtS  = aggS + NPB * LDA;                  // [64][LDA]  wtS[c][k] = w[k][c]
  float* invS = (float*)(smem + (size_t)2 * NPB * LDA * sizeof(__hip_bfloat16));

  const int tid   = threadIdx.x;
  const int lane  = tid & 63;
  const int wvid  = tid >> 6;              // 0..7
  const int node0 = blockIdx.x * NPB;

  // ---- runtime dtype detection (block-uniform, ~free) ----
  // bf16 data: low 16 bits of word i = a real bf16 of N(0,1) -> exp in [96,160).
  // fp32 data: low 16 bits = uniform mantissa bits -> in-range only ~25%.
  const unsigned xword = ((const unsigned*)xv)[lane];
  const int exf = (int)((xword >> 7) & 0xFFu);
  const bool x_bf16 = __popcll(__ballot(exf >= 96 && exf < 160)) >= 48;
  // int64 ptr read as int32: word[1] = high(ptr[0]) = 0. int32 ptr: ptr[1] = DEG > 0.
  const bool idx64 = (p32[1] == 0);

  // ---- stage W^T into LDS ----
  if (x_bf16) {
    const __hip_bfloat16* wb = (const __hip_bfloat16*)wv;
    for (int i = tid; i < KDIM * 64; i += THREADS)
      wtS[(i & 63) * LDA + (i >> 6)] = wb[i];
  } else {
    const float* wf = (const float*)wv;
    for (int i = tid; i < KDIM * 64; i += THREADS)
      wtS[(i & 63) * LDA + (i >> 6)] = __float2bfloat16(wf[i]);
  }

  // ---- gather phase: wave wvid owns nodes nl = wvid*8 .. wvid*8+7 ----
  auto gather = [&](auto xp) {
    for (int nn = 0; nn < NPB / 8; ++nn) {
      const int nl   = wvid * (NPB / 8) + nn;
      const int node = node0 + nl;
      float a0 = 0.f, a1 = 0.f, a2 = 0.f, a3 = 0.f,
            a4 = 0.f, a5 = 0.f, a6 = 0.f, a7 = 0.f;
      int deg = 0;
      if (node < num_nodes) {
        const int e0 = idx64 ? p32[2 * node]     : p32[node];
        const int e1 = idx64 ? p32[2 * node + 2] : p32[node + 1];
        deg = e1 - e0;
        if (deg == 12) {
          // fast path (this dataset: uniform degree 12) -> fully unrolled,
          // 12 independent coalesced 256B x-row loads in flight per wave
          int ms = 0, mr = 0;
          if (lane < 12) {
            const int e = e0 + lane;
            ms = idx64 ? i32[2 * e] : i32[e];
            mr = idx64 ? t32[2 * e] : t32[e];
          }
#pragma unroll
          for (int j = 0; j < 12; ++j) {
            const int src = __shfl(ms, j);
            const int r   = __builtin_amdgcn_readfirstlane(__shfl(mr, j));
            const float v = (float)xp[(size_t)src * 64 + lane];
            ACC_SWITCH(r, v)
          }
        } else if (deg > 0) {
          for (int base = e0; base < e1; base += 64) {
            const int n = min(64, e1 - base);
            int ms = 0, mr = 0;
            if (lane < n) {
              const int e = base + lane;
              ms = idx64 ? i32[2 * e] : i32[e];
              mr = idx64 ? t32[2 * e] : t32[e];
            }
            for (int j = 0; j < n; ++j) {
              const int src = __shfl(ms, j);
              const int r   = __builtin_amdgcn_readfirstlane(__shfl(mr, j));
              const float v = (float)xp[(size_t)src * 64 + lane];
              ACC_SWITCH(r, v)
            }
          }
        }
      }
      // write agg row (zeros for out-of-range nodes), lane c -> k = r*64 + c
      aggS[nl * LDA + 0 * 64 + lane] = __float2bfloat16(a0);
      aggS[nl * LDA + 1 * 64 + lane] = __float2bfloat16(a1);
      aggS[nl * LDA + 2 * 64 + lane] = __float2bfloat16(a2);
      aggS[nl * LDA + 3 * 64 + lane] = __float2bfloat16(a3);
      aggS[nl * LDA + 4 * 64 + lane] = __float2bfloat16(a4);
      aggS[nl * LDA + 5 * 64 + lane] = __float2bfloat16(a5);
      aggS[nl * LDA + 6 * 64 + lane] = __float2bfloat16(a6);
      aggS[nl * LDA + 7 * 64 + lane] = __float2bfloat16(a7);
      if (lane == 0) invS[nl] = (deg > 0) ? (1.0f / (float)deg) : 0.0f;
    }
  };
  if (x_bf16) gather((const __hip_bfloat16*)xv);
  else        gather((const float*)xv);

  __syncthreads();

  // ---- MFMA phase: out_tile[64x64] = agg[64x512] @ Wcat[512x64] ----
  const int mt  = wvid >> 1;
  const int nt0 = (wvid & 1) * 2;
  const int mi  = lane & 15;        // m for A / n for B / col for D
  const int q   = lane >> 4;
  const __hip_bfloat16* ap  = aggS + (mt * 16 + mi) * LDA + q * 8;
  const __hip_bfloat16* bp0 = wtS  + ((nt0 + 0) * 16 + mi) * LDA + q * 8;
  const __hip_bfloat16* bp1 = wtS  + ((nt0 + 1) * 16 + mi) * LDA + q * 8;
  f32x4 c0 = {0.f, 0.f, 0.f, 0.f};
  f32x4 c1 = {0.f, 0.f, 0.f, 0.f};
#pragma unroll
  for (int kt = 0; kt < KDIM / 32; ++kt) {
    const bf16x8 a  = *(const bf16x8*)(ap  + kt * 32);
    const bf16x8 b0 = *(const bf16x8*)(bp0 + kt * 32);
    const bf16x8 b1 = *(const bf16x8*)(bp1 + kt * 32);
    c0 = __builtin_amdgcn_mfma_f32_16x16x32_bf16(a, b0, c0, 0, 0, 0);
    c1 = __builtin_amdgcn_mfma_f32_16x16x32_bf16(a, b1, c1, 0, 0, 0);
  }

  // D layout: col = lane&15, row = q*4 + reg  -> fp32 stores
#pragma unroll
  for (int i = 0; i < 4; ++i) {
    const int row  = q * 4 + i;
    const int nl   = mt * 16 + row;
    const int node = node0 + nl;
    if (node < num_nodes) {
      const float s = invS[nl];
      out[(size_t)node * 64 + (nt0 + 0) * 16 + mi] = c0[i] * s;
      out[(size_t)node * 64 + (nt0 + 1) * 16 + mi] = c1[i] * s;
    }
  }
}

extern "C" void kernel_launch(void* const* d_in, const int* in_sizes, int n_in,
                              void* d_out, int out_size, void* d_ws, size_t ws_size,
                              hipStream_t stream) {
  const void* x   = d_in[0];
  const void* w   = d_in[1];
  const int*  ptr = (const int*)d_in[2];
  const int*  idx = (const int*)d_in[3];
  const int*  et  = (const int*)d_in[4];
  float*      out = (float*)d_out;

  const int num_nodes = in_sizes[0] / 64;   // x is [N, 64]
  const size_t lds_bytes =
      (size_t)2 * NPB * LDA * sizeof(__hip_bfloat16) + NPB * sizeof(float);

  hipFuncSetAttribute((const void*)rgcn_fused,
                      hipFuncAttributeMaxDynamicSharedMemorySize,
                      (int)lds_bytes);

  const int nblocks = (num_nodes + NPB - 1) / NPB;
  rgcn_fused<<<nblocks, THREADS, lds_bytes, stream>>>(x, w, ptr, idx, et, out,
                                                      num_nodes);
}

// Round 4
// 224.110 us; speedup vs baseline: 1.7626x; 1.7626x over previous
//
#include <hip/hip_runtime.h>
#include <hip/hip_bf16.h>

// RGCN fused: aggregate-per-relation (gather, fp32 acc) -> MFMA GEMM (K=8*64=512).
// x/linear fp32 on device, output fp32 (established rounds 1-3). Round 4:
// latency-bound fix — stage edge meta in LDS, batch 48 gather loads per wave
// (4 nodes x 12 edges) with no branches between loads for full MLP.
// Occupancy is LDS-bound (1 block/CU, 8 waves) so high VGPR use is free.

#define THREADS 512
#define NPB 64            // nodes per block
#define KDIM 512          // NUM_REL * IN_CH
#define LDA 520           // padded bf16 row stride (1040 B = 16B-aligned)
#define MAXE 1024         // LDS meta capacity (uniform deg 12 -> 768 used)

typedef __attribute__((ext_vector_type(8))) short bf16x8;
typedef __attribute__((ext_vector_type(4))) float f32x4;

extern __shared__ __align__(16) char smem[];

#define ACC_SW(accrow, r, vv)                                        \
  switch (r) {                                                       \
    case 0: accrow[0] += (vv); break; case 1: accrow[1] += (vv); break; \
    case 2: accrow[2] += (vv); break; case 3: accrow[3] += (vv); break; \
    case 4: accrow[4] += (vv); break; case 5: accrow[5] += (vv); break; \
    case 6: accrow[6] += (vv); break; default: accrow[7] += (vv); break; }

__global__ __launch_bounds__(THREADS, 1)
void rgcn_fused(const void* __restrict__ xv,
                const void* __restrict__ wv,    // [512][64] = [r*64+k_in][c_out]
                const int* __restrict__ p32,
                const int* __restrict__ i32,
                const int* __restrict__ t32,
                float* __restrict__ out,
                int num_nodes) {
  __hip_bfloat16* aggS = (__hip_bfloat16*)smem;             // [NPB][LDA]
  __hip_bfloat16* wtS  = aggS + NPB * LDA;                  // [64][LDA]
  char* tail = smem + (size_t)2 * NPB * LDA * sizeof(__hip_bfloat16);
  float*    invS  = (float*)tail;                           // [64]
  int*      ptrS  = (int*)(tail + 256);                     // [65]
  unsigned* eMeta = (unsigned*)(tail + 256 + 272);          // [MAXE] (r<<24)|src

  const int tid   = threadIdx.x;
  const int lane  = tid & 63;
  const int wvid  = tid >> 6;              // 0..7
  const int node0 = blockIdx.x * NPB;

  // ---- runtime dtype / index-width detection (block-uniform) ----
  const unsigned xword = ((const unsigned*)xv)[lane];
  const int exf = (int)((xword >> 7) & 0xFFu);
  const bool x_bf16 = __popcll(__ballot(exf >= 96 && exf < 160)) >= 48;
  const bool idx64 = (p32[1] == 0);

  auto ldptr = [&](int n) -> int { return idx64 ? p32[2 * n] : p32[n]; };

  const int ntop   = min(node0 + NPB, num_nodes);
  const int e_lo   = ldptr(node0);
  const int e_hi   = ldptr(ntop);
  const int ecount = e_hi - e_lo;
  const bool staged = (ecount > 0 && ecount <= MAXE);

  // ---- stage per-node ptr ----
  for (int i = tid; i <= NPB; i += THREADS)
    ptrS[i] = ldptr(min(node0 + i, num_nodes));

  // ---- stage packed edge meta: (rel<<24)|src ----
  if (staged) {
    for (int e = tid; e < ecount; e += THREADS) {
      const int ge = e_lo + e;
      const unsigned s = (unsigned)(idx64 ? i32[2 * ge] : i32[ge]);
      const unsigned r = (unsigned)(idx64 ? t32[2 * ge] : t32[ge]);
      eMeta[e] = s | (r << 24);
    }
  }

  // ---- stage W^T into LDS (bf16) ----
  if (x_bf16) {
    const __hip_bfloat16* wb = (const __hip_bfloat16*)wv;
    for (int i = tid; i < KDIM * 64; i += THREADS)
      wtS[(i & 63) * LDA + (i >> 6)] = wb[i];
  } else {
    const float* wf = (const float*)wv;
    for (int i = tid; i < KDIM * 64; i += THREADS)
      wtS[(i & 63) * LDA + (i >> 6)] = __float2bfloat16(wf[i]);
  }

  __syncthreads();

  // ---- gather: wave owns 8 nodes, processed as 2 groups of 4 ----
  auto gather = [&](auto xp) {
    // generic (any degree) fallback, correct for boundary / non-12 / unstaged
    auto node_generic = [&](int nl, float* acc) {
      const int e0 = ptrS[nl] - e_lo, e1 = ptrS[nl + 1] - e_lo;
      for (int e = e0; e < e1; ++e) {
        unsigned mm;
        if (staged) mm = eMeta[e];
        else {
          const int ge = e_lo + e;
          mm = (unsigned)(idx64 ? i32[2 * ge] : i32[ge]) |
               ((unsigned)(idx64 ? t32[2 * ge] : t32[ge]) << 24);
        }
        const float vv = (float)xp[(size_t)(int)(mm & 0x00FFFFFFu) * 64 + lane];
        const int r = __builtin_amdgcn_readfirstlane((int)(mm >> 24));
        ACC_SW(acc, r, vv)
      }
    };

#pragma unroll
    for (int g = 0; g < 2; ++g) {
      const int nlb = wvid * 8 + g * 4;
      float acc[4][8];
#pragma unroll
      for (int t = 0; t < 4; ++t)
#pragma unroll
        for (int r = 0; r < 8; ++r) acc[t][r] = 0.f;

      int e0s[4];
      bool fast = staged && (node0 + nlb + 3 < num_nodes);
#pragma unroll
      for (int t = 0; t < 4; ++t) {
        e0s[t] = ptrS[nlb + t] - e_lo;
        const int d = ptrS[nlb + t + 1] - e_lo - e0s[t];
        fast = fast && (d == 12);
      }

      if (fast) {
        // phase 1: 48 meta reads from LDS (broadcast, conflict-free)
        unsigned m[48];
#pragma unroll
        for (int t = 0; t < 4; ++t)
#pragma unroll
          for (int j = 0; j < 12; ++j) m[t * 12 + j] = eMeta[e0s[t] + j];
        // phase 2: 48 independent coalesced 256B x-row loads, all in flight
        float v[48];
#pragma unroll
        for (int i = 0; i < 48; ++i)
          v[i] = (float)xp[(size_t)(int)(m[i] & 0x00FFFFFFu) * 64 + lane];
        // phase 3: accumulate (wave-uniform scalar branches, off VALU pipe)
#pragma unroll
        for (int t = 0; t < 4; ++t)
#pragma unroll
          for (int j = 0; j < 12; ++j) {
            const int r = __builtin_amdgcn_readfirstlane((int)(m[t * 12 + j] >> 24));
            const float vv = v[t * 12 + j];
            ACC_SW(acc[t], r, vv)
          }
      } else {
#pragma unroll
        for (int t = 0; t < 4; ++t)
          if (node0 + nlb + t < num_nodes) node_generic(nlb + t, acc[t]);
      }

      // write agg rows (bf16) + inverse degree
#pragma unroll
      for (int t = 0; t < 4; ++t) {
        const int nl = nlb + t;
#pragma unroll
        for (int r = 0; r < 8; ++r)
          aggS[nl * LDA + r * 64 + lane] = __float2bfloat16(acc[t][r]);
        if (lane == 0) {
          const int d = ptrS[nl + 1] - ptrS[nl];
          invS[nl] = (d > 0 && node0 + nl < num_nodes) ? 1.0f / (float)d : 0.0f;
        }
      }
    }
  };
  if (x_bf16) gather((const __hip_bfloat16*)xv);
  else        gather((const float*)xv);

  __syncthreads();

  // ---- MFMA phase: out_tile[64x64] = agg[64x512] @ Wcat[512x64] ----
  const int mt  = wvid >> 1;
  const int nt0 = (wvid & 1) * 2;
  const int mi  = lane & 15;
  const int q   = lane >> 4;
  const __hip_bfloat16* ap  = aggS + (mt * 16 + mi) * LDA + q * 8;
  const __hip_bfloat16* bp0 = wtS  + ((nt0 + 0) * 16 + mi) * LDA + q * 8;
  const __hip_bfloat16* bp1 = wtS  + ((nt0 + 1) * 16 + mi) * LDA + q * 8;
  f32x4 c0 = {0.f, 0.f, 0.f, 0.f};
  f32x4 c1 = {0.f, 0.f, 0.f, 0.f};
#pragma unroll
  for (int kt = 0; kt < KDIM / 32; ++kt) {
    const bf16x8 a  = *(const bf16x8*)(ap  + kt * 32);
    const bf16x8 b0 = *(const bf16x8*)(bp0 + kt * 32);
    const bf16x8 b1 = *(const bf16x8*)(bp1 + kt * 32);
    c0 = __builtin_amdgcn_mfma_f32_16x16x32_bf16(a, b0, c0, 0, 0, 0);
    c1 = __builtin_amdgcn_mfma_f32_16x16x32_bf16(a, b1, c1, 0, 0, 0);
  }

  // D layout: col = lane&15, row = q*4 + reg -> fp32 stores
#pragma unroll
  for (int i = 0; i < 4; ++i) {
    const int row  = q * 4 + i;
    const int nl   = mt * 16 + row;
    const int node = node0 + nl;
    if (node < num_nodes) {
      const float s = invS[nl];
      out[(size_t)node * 64 + (nt0 + 0) * 16 + mi] = c0[i] * s;
      out[(size_t)node * 64 + (nt0 + 1) * 16 + mi] = c1[i] * s;
    }
  }
}

extern "C" void kernel_launch(void* const* d_in, const int* in_sizes, int n_in,
                              void* d_out, int out_size, void* d_ws, size_t ws_size,
                              hipStream_t stream) {
  const void* x   = d_in[0];
  const void* w   = d_in[1];
  const int*  ptr = (const int*)d_in[2];
  const int*  idx = (const int*)d_in[3];
  const int*  et  = (const int*)d_in[4];
  float*      out = (float*)d_out;

  const int num_nodes = in_sizes[0] / 64;   // x is [N, 64]
  const size_t lds_bytes =
      (size_t)2 * NPB * LDA * sizeof(__hip_bfloat16) + 256 + 272 +
      (size_t)MAXE * sizeof(unsigned);

  hipFuncSetAttribute((const void*)rgcn_fused,
                      hipFuncAttributeMaxDynamicSharedMemorySize,
                      (int)lds_bytes);

  const int nblocks = (num_nodes + NPB - 1) / NPB;
  rgcn_fused<<<nblocks, THREADS, lds_bytes, stream>>>(x, w, ptr, idx, et, out,
                                                      num_nodes);
}

// Round 5
// 136.834 us; speedup vs baseline: 2.8868x; 1.6378x over previous
//
#include <hip/hip_runtime.h>
#include <hip/hip_bf16.h>

// RGCN fused: per-relation aggregate (gather, fp32 acc) -> MFMA GEMM (K=8*64=512).
// x/linear fp32 on device, fp32 out (established r1-r3). Round 5:
//  - W evicted from LDS: pack_w pre-packs bf16 B-fragments into d_ws (L2-hot)
//    -> LDS 71 KB -> 2 blocks/CU (16 waves) instead of 1 (8 waves).
//  - Gather: quad-parallel float4 loads (12 dwordx4 per 4-node group, single
//    basic block -> all in flight), branchless predicated-FMA relation dispatch.
// __launch_bounds__(512,2) caps VGPR at 128 to guarantee 2 blocks/CU.

#define THREADS 512
#define NPB 64            // nodes per block
#define KDIM 512          // NUM_REL * IN_CH
#define LDA 520           // padded bf16 row stride (1040 B)
#define MAXE 1024         // LDS edge-meta capacity (deg 12 -> 768 used)
#define WFRAG (4 * 16 * 64 * 8)   // 32768 bf16 B-fragment elements

typedef __attribute__((ext_vector_type(8))) short bf16x8;
typedef __attribute__((ext_vector_type(4))) float f32x4;

extern __shared__ __align__(16) char smem[];

__device__ __forceinline__ unsigned short f2bf(float f) {
  __hip_bfloat16 h = __float2bfloat16(f);
  return *reinterpret_cast<unsigned short*>(&h);
}

// ---- pack W (fp32 or bf16, [512][64]) -> bf16 B-fragment order in ws ----
// frag element i = ((nt*16+kt)*64 + lane)*8 + j  holds  W[kt*32+(lane>>4)*8+j][nt*16+(lane&15)]
__global__ __launch_bounds__(256) void pack_w(const void* __restrict__ wv,
                                              unsigned short* __restrict__ wsB) {
  const int lane = threadIdx.x & 63;
  const unsigned word = ((const unsigned*)wv)[lane];
  const int exf = (int)((word >> 7) & 0xFFu);
  const bool w_bf16 = __popcll(__ballot(exf >= 96 && exf < 160)) >= 48;
  for (int i = blockIdx.x * 256 + threadIdx.x; i < WFRAG; i += gridDim.x * 256) {
    const int j  = i & 7;
    const int l  = (i >> 3) & 63;
    const int kt = (i >> 9) & 15;
    const int nt = i >> 13;
    const int k  = kt * 32 + (l >> 4) * 8 + j;
    const int n  = nt * 16 + (l & 15);
    float v;
    if (w_bf16) v = __bfloat162float(((const __hip_bfloat16*)wv)[k * 64 + n]);
    else        v = ((const float*)wv)[k * 64 + n];
    wsB[i] = f2bf(v);
  }
}

#define ACC_SW(accrow, r, vv)                                        \
  switch (r) {                                                       \
    case 0: accrow[0] += (vv); break; case 1: accrow[1] += (vv); break; \
    case 2: accrow[2] += (vv); break; case 3: accrow[3] += (vv); break; \
    case 4: accrow[4] += (vv); break; case 5: accrow[5] += (vv); break; \
    case 6: accrow[6] += (vv); break; default: accrow[7] += (vv); break; }

__global__ __launch_bounds__(THREADS, 2)
void rgcn_fused(const void* __restrict__ xv,
                const void* __restrict__ wv,
                const int* __restrict__ p32,
                const int* __restrict__ i32,
                const int* __restrict__ t32,
                const unsigned short* __restrict__ wsB,  // null -> W staged in LDS
                float* __restrict__ out,
                int num_nodes) {
  __hip_bfloat16* aggS = (__hip_bfloat16*)smem;                 // [NPB][LDA]
  __hip_bfloat16* wtS  = aggS + NPB * LDA;                      // only if !wsB
  char* tail = smem + (size_t)NPB * LDA * 2 + (wsB ? 0 : (size_t)64 * LDA * 2);
  float*    invS  = (float*)tail;                               // [64]
  int*      ptrS  = (int*)(tail + 256);                         // [65]
  unsigned* eMeta = (unsigned*)(tail + 256 + 272);              // [MAXE]

  const int tid   = threadIdx.x;
  const int lane  = tid & 63;
  const int wvid  = tid >> 6;
  const int node0 = blockIdx.x * NPB;

  // runtime dtype / index-width detection (block-uniform)
  const unsigned xword = ((const unsigned*)xv)[lane];
  const int exf = (int)((xword >> 7) & 0xFFu);
  const bool x_bf16 = __popcll(__ballot(exf >= 96 && exf < 160)) >= 48;
  const bool idx64 = (p32[1] == 0);

  auto ldptr = [&](int n) -> int { return idx64 ? p32[2 * n] : p32[n]; };

  const int ntop   = min(node0 + NPB, num_nodes);
  const int e_lo   = ldptr(node0);
  const int ecount = ldptr(ntop) - e_lo;
  const bool staged = (ecount > 0 && ecount <= MAXE);

  for (int i = tid; i <= NPB; i += THREADS)
    ptrS[i] = ldptr(min(node0 + i, num_nodes));

  if (staged) {
    for (int e = tid; e < ecount; e += THREADS) {
      const int ge = e_lo + e;
      const unsigned s = (unsigned)(idx64 ? i32[2 * ge] : i32[ge]);
      const unsigned r = (unsigned)(idx64 ? t32[2 * ge] : t32[ge]);
      eMeta[e] = s | (r << 24);
    }
  }

  if (!wsB) {  // fallback: stage W^T in LDS (rare; only if ws too small)
    if (x_bf16) {
      const __hip_bfloat16* wb = (const __hip_bfloat16*)wv;
      for (int i = tid; i < KDIM * 64; i += THREADS)
        wtS[(i & 63) * LDA + (i >> 6)] = wb[i];
    } else {
      const float* wf = (const float*)wv;
      for (int i = tid; i < KDIM * 64; i += THREADS)
        wtS[(i & 63) * LDA + (i >> 6)] = __float2bfloat16(wf[i]);
    }
  }

  __syncthreads();

  // inverse degree (reads ptrS; consumed after next barrier)
  for (int i = tid; i < NPB; i += THREADS) {
    const int d = ptrS[i + 1] - ptrS[i];
    invS[i] = (d > 0 && node0 + i < num_nodes) ? 1.0f / (float)d : 0.0f;
  }

  const int c16 = lane & 15;
  const int qd  = lane >> 4;

  // ---- gather: wave owns 8 nodes = 2 groups of 4; quad qd owns node nlb+qd ----
  auto gather = [&](auto xp, auto loadrow) {
#pragma unroll
    for (int g = 0; g < 2; ++g) {
      const int nlb = wvid * 8 + g * 4;
      const int eq0 = ptrS[nlb + qd] - e_lo;          // quad-uniform per lane
      const int dq  = ptrS[nlb + qd + 1] - e_lo - eq0;
      const bool okfast = staged && (node0 + nlb + 3 < num_nodes) &&
                          (__ballot(dq == 12) == ~0ull);
      if (okfast) {
        // phase 1: meta from LDS (4 distinct addrs, broadcast within quad)
        unsigned m[12];
#pragma unroll
        for (int j = 0; j < 12; ++j) m[j] = eMeta[eq0 + j];
        // phase 2: 12 independent dwordx4 loads (1 KB each), all in flight
        float4 v[12];
#pragma unroll
        for (int j = 0; j < 12; ++j)
          v[j] = loadrow((int)(m[j] & 0x00FFFFFFu), c16);
        // phase 3: branchless predicated accumulate (8 rel x 4 ch FMAs)
        float4 acc[8];
#pragma unroll
        for (int r = 0; r < 8; ++r) acc[r] = make_float4(0.f, 0.f, 0.f, 0.f);
#pragma unroll
        for (int j = 0; j < 12; ++j) {
          const unsigned rj = m[j] >> 24;
#pragma unroll
          for (int r = 0; r < 8; ++r) {
            const float mk = (rj == (unsigned)r) ? 1.0f : 0.0f;
            acc[r].x += mk * v[j].x;
            acc[r].y += mk * v[j].y;
            acc[r].z += mk * v[j].z;
            acc[r].w += mk * v[j].w;
          }
        }
        // write: quad qd -> node nlb+qd, channels 4*c16..+3 (8-B stores)
        unsigned short* dst = (unsigned short*)(aggS + (nlb + qd) * LDA) + 4 * c16;
#pragma unroll
        for (int r = 0; r < 8; ++r) {
          ushort4 b;
          b.x = f2bf(acc[r].x); b.y = f2bf(acc[r].y);
          b.z = f2bf(acc[r].z); b.w = f2bf(acc[r].w);
          *(ushort4*)(dst + r * 64) = b;
        }
      } else {
        // generic: full wave per node, lane = channel, wave-uniform switch
#pragma unroll
        for (int t = 0; t < 4; ++t) {
          const int nl = nlb + t;
          float a[8] = {0.f, 0.f, 0.f, 0.f, 0.f, 0.f, 0.f, 0.f};
          if (node0 + nl < num_nodes) {
            const int e0 = ptrS[nl] - e_lo, e1 = ptrS[nl + 1] - e_lo;
            for (int e = e0; e < e1; ++e) {
              unsigned mm;
              if (staged) mm = eMeta[e];
              else {
                const int ge = e_lo + e;
                mm = (unsigned)(idx64 ? i32[2 * ge] : i32[ge]) |
                     ((unsigned)(idx64 ? t32[2 * ge] : t32[ge]) << 24);
              }
              const float vv = (float)xp[(size_t)(mm & 0x00FFFFFFu) * 64 + lane];
              const int r = __builtin_amdgcn_readfirstlane((int)(mm >> 24));
              ACC_SW(a, r, vv)
            }
          }
#pragma unroll
          for (int r = 0; r < 8; ++r)
            aggS[nl * LDA + r * 64 + lane] = __float2bfloat16(a[r]);
        }
      }
    }
  };

  if (x_bf16) {
    const __hip_bfloat16* xb = (const __hip_bfloat16*)xv;
    auto lr = [&](int src, int c) -> float4 {
      const ushort4 u = ((const ushort4*)xv)[src * 16 + c];
      float4 f;
      f.x = __uint_as_float((unsigned)(unsigned short)u.x << 16);
      f.y = __uint_as_float((unsigned)(unsigned short)u.y << 16);
      f.z = __uint_as_float((unsigned)(unsigned short)u.z << 16);
      f.w = __uint_as_float((unsigned)(unsigned short)u.w << 16);
      return f;
    };
    gather(xb, lr);
  } else {
    const float* xf = (const float*)xv;
    auto lr = [&](int src, int c) -> float4 {
      return ((const float4*)xv)[src * 16 + c];
    };
    gather(xf, lr);
  }

  __syncthreads();

  // ---- MFMA: out_tile[64x64] = agg[64x512] @ Wcat[512x64] ----
  const int mt  = wvid >> 1;
  const int nt0 = (wvid & 1) * 2;
  const int mi  = lane & 15;
  const int q4  = lane >> 4;
  const __hip_bfloat16* ap = aggS + (mt * 16 + mi) * LDA + q4 * 8;
  f32x4 c0 = {0.f, 0.f, 0.f, 0.f};
  f32x4 c1 = {0.f, 0.f, 0.f, 0.f};
  if (wsB) {
    const bf16x8* B = (const bf16x8*)wsB;
#pragma unroll
    for (int kt = 0; kt < KDIM / 32; ++kt) {
      const bf16x8 a  = *(const bf16x8*)(ap + kt * 32);
      const bf16x8 b0 = B[((nt0 + 0) * 16 + kt) * 64 + lane];
      const bf16x8 b1 = B[((nt0 + 1) * 16 + kt) * 64 + lane];
      c0 = __builtin_amdgcn_mfma_f32_16x16x32_bf16(a, b0, c0, 0, 0, 0);
      c1 = __builtin_amdgcn_mfma_f32_16x16x32_bf16(a, b1, c1, 0, 0, 0);
    }
  } else {
    const __hip_bfloat16* bp0 = wtS + ((nt0 + 0) * 16 + mi) * LDA + q4 * 8;
    const __hip_bfloat16* bp1 = wtS + ((nt0 + 1) * 16 + mi) * LDA + q4 * 8;
#pragma unroll
    for (int kt = 0; kt < KDIM / 32; ++kt) {
      const bf16x8 a  = *(const bf16x8*)(ap  + kt * 32);
      const bf16x8 b0 = *(const bf16x8*)(bp0 + kt * 32);
      const bf16x8 b1 = *(const bf16x8*)(bp1 + kt * 32);
      c0 = __builtin_amdgcn_mfma_f32_16x16x32_bf16(a, b0, c0, 0, 0, 0);
      c1 = __builtin_amdgcn_mfma_f32_16x16x32_bf16(a, b1, c1, 0, 0, 0);
    }
  }

  // D layout: col = lane&15, row = q4*4 + reg -> fp32 stores
#pragma unroll
  for (int i = 0; i < 4; ++i) {
    const int row  = q4 * 4 + i;
    const int nl   = mt * 16 + row;
    const int node = node0 + nl;
    if (node < num_nodes) {
      const float s = invS[nl];
      out[(size_t)node * 64 + (nt0 + 0) * 16 + mi] = c0[i] * s;
      out[(size_t)node * 64 + (nt0 + 1) * 16 + mi] = c1[i] * s;
    }
  }
}

extern "C" void kernel_launch(void* const* d_in, const int* in_sizes, int n_in,
                              void* d_out, int out_size, void* d_ws, size_t ws_size,
                              hipStream_t stream) {
  const void* x   = d_in[0];
  const void* w   = d_in[1];
  const int*  ptr = (const int*)d_in[2];
  const int*  idx = (const int*)d_in[3];
  const int*  et  = (const int*)d_in[4];
  float*      out = (float*)d_out;

  const int num_nodes = in_sizes[0] / 64;   // x is [N, 64]

  const bool useWs = (d_ws != nullptr) &&
                     (ws_size >= (size_t)WFRAG * sizeof(unsigned short));
  unsigned short* wsB = useWs ? (unsigned short*)d_ws : nullptr;
  if (useWs) pack_w<<<32, 256, 0, stream>>>(w, wsB);

  const size_t lds_bytes = (size_t)NPB * LDA * 2 +
                           (useWs ? 0 : (size_t)64 * LDA * 2) +
                           256 + 272 + (size_t)MAXE * 4;

  hipFuncSetAttribute((const void*)rgcn_fused,
                      hipFuncAttributeMaxDynamicSharedMemorySize,
                      (int)lds_bytes);

  const int nblocks = (num_nodes + NPB - 1) / NPB;
  rgcn_fused<<<nblocks, THREADS, lds_bytes, stream>>>(x, w, ptr, idx, et, wsB,
                                                      out, num_nodes);
}